// Round 3
// baseline (260.156 us; speedup 1.0000x reference)
//
#include <hip/hip_runtime.h>
#include <float.h>
#include <stdint.h>

// SOM2D argmin ||x-w||^2 via split-f16 MFMA. N=32768, M=4096, D=128.
//
// score = ||w||^2 - 2 x.w  (||x||^2 constant per sample: dropped)
// cross = xh*wh + xl*wh + xh*wl  (f16 hi/lo split, fp32 accum; |err|~2e-5)
//
// Round-9: accumulator double-buffering. Round-6/8 analysis: score(tt) has a
// true dep on tile tt's 96 MFMAs AND tile tt+1's MFMAs have a WAR dep on
// score(tt) (same acc regs) -> each wave alternates MFMA-burst / pipe-idle
// VALU tail, and the 2 co-resident waves do it in lockstep (MfmaUtil 36-48%).
// Fix (T15 mechanism): accA/accB alternated by a 2-unrolled tile loop; the
// score of tile tt-1 is placed INSIDE tile tt's MFMA region, so its ~110
// VALU ops issue in the free slots between MFMA issues (matrix pipe stays
// fed). +32 regs on the unified file: free, since LDS (64KB/block) caps
// occupancy at 2 waves/SIMD anyway.
// Also: ||w||^2 folded into acc init (acc = -wq/2; score = -2*acc, exact
// recovery at the end) -> 64 fewer fmaf per tile in the tail.
// Setprio removed (round-8: harmful on lockstep structure). B loads back to
// round-6 placement (compiler already sinks them optimally: VGPR 116 < live
// estimate proved it). Fused atomicMin finalize kept (verified r7/r8).

constexpr int D = 128;

typedef _Float16 f16x8 __attribute__((ext_vector_type(8)));
typedef float    f32x4 __attribute__((ext_vector_type(4)));

__device__ __forceinline__ void cvt_split(const float4& a0, const float4& a1,
                                          f16x8& h, f16x8& l) {
    float v[8] = {a0.x, a0.y, a0.z, a0.w, a1.x, a1.y, a1.z, a1.w};
#pragma unroll
    for (int j = 0; j < 8; ++j) {
        _Float16 hh = (_Float16)v[j];
        h[j] = hh;
        l[j] = (_Float16)(v[j] - (float)hh);
    }
}

// W (M x D fp32) -> frag-major hi/lo f16 + wsq. Thread = (unit u, k-octet o).
// Granule slot for (u, k=8o..8o+7), n-tile = 32 units:
//   T=u>>5, t=(u>>4)&1, c=u&15, s=o>>2, q=o&3
//   slot = T*512 + s*128 + t*64 + q*16 + c
// Main-loop read: tile_base(T*512) + s*128 + t*64 + lane. Sequential 1KB/instr.
// Also inits keys (u64 max) and per-sample-group completion counters.
__global__ __launch_bounds__(256) void prep_kernel(
        const float* __restrict__ w, f16x8* __restrict__ hG,
        f16x8* __restrict__ lG, float* __restrict__ wsq, int M,
        unsigned long long* __restrict__ keys, unsigned* __restrict__ cnt,
        int N, int nGroups) {
    int g = blockIdx.x * 256 + threadIdx.x;
    if (keys && g < N) keys[g] = ~0ull;
    if (cnt && g < nGroups) cnt[g] = 0u;
    if (g >= M * 16) return;
    int u = g >> 4, o = g & 15;
    const float4* wp = reinterpret_cast<const float4*>(w + (size_t)u * D + o * 8);
    float4 a0 = wp[0], a1 = wp[1];
    f16x8 h, l;
    cvt_split(a0, a1, h, l);
    float ss = 0.f;
    ss = fmaf(a0.x, a0.x, ss); ss = fmaf(a0.y, a0.y, ss);
    ss = fmaf(a0.z, a0.z, ss); ss = fmaf(a0.w, a0.w, ss);
    ss = fmaf(a1.x, a1.x, ss); ss = fmaf(a1.y, a1.y, ss);
    ss = fmaf(a1.z, a1.z, ss); ss = fmaf(a1.w, a1.w, ss);
#pragma unroll
    for (int m = 1; m < 16; m <<= 1) ss += __shfl_xor(ss, m, 64);
    if (o == 0) wsq[u] = ss;
    int slot = ((u >> 5) << 9) + ((o >> 2) << 7) + (((u >> 4) & 1) << 6)
             + ((o & 3) << 4) + (u & 15);
    hG[slot] = h;
    lG[slot] = l;
}

// argmax over acc' (acc' = -wq/2 + x.w; score = -2*acc' is argmin-equivalent).
// Strict > keeps the first (lowest-index) winner, matching score< semantics.
__device__ __forceinline__ void score_block(
        const f32x4 (&acc)[8], int tile, int c,
        float (&bestD)[16], int (&bestI)[16]) {
    const int uTile = tile * 32;
#pragma unroll
    for (int t = 0; t < 2; ++t) {
        const int n = uTile + 16 * t + c;
#pragma unroll
        for (int i = 0; i < 4; ++i) {
            f32x4 a = acc[i * 2 + t];
#pragma unroll
            for (int r = 0; r < 4; ++r) {
                int sl = i * 4 + r;
                if (a[r] > bestD[sl]) { bestD[sl] = a[r]; bestI[sl] = n; }
            }
        }
    }
}

// One tile: 96 MFMAs into cur; score of prev tile interleaved mid-burst.
template <bool SCORE_PREV>
__device__ __forceinline__ void tile_step(
        const f16x8 (&Ah)[16], const f16x8* myAl, int lane, int c,
        const f16x8* __restrict__ hG, const f16x8* __restrict__ lG,
        const float* __restrict__ wsq, int tile,
        f32x4 (&cur)[8], const f32x4 (&prev)[8], int prevTile,
        float (&bestD)[16], int (&bestI)[16]) {
    const f16x8* hp = hG + ((size_t)tile << 9) + lane;
    const f16x8* lp = lG + ((size_t)tile << 9) + lane;
    f16x8 bh[8], bl[8];
#pragma unroll
    for (int s = 0; s < 4; ++s)
#pragma unroll
        for (int t = 0; t < 2; ++t) {
            bh[s * 2 + t] = hp[s * 128 + t * 64];
            bl[s * 2 + t] = lp[s * 128 + t * 64];
        }

    const int uTile = tile * 32;
    const float m0 = -0.5f * wsq[uTile + c];
    const float m1 = -0.5f * wsq[uTile + 16 + c];
#pragma unroll
    for (int i = 0; i < 4; ++i) {
        cur[i * 2 + 0] = (f32x4){m0, m0, m0, m0};
        cur[i * 2 + 1] = (f32x4){m1, m1, m1, m1};
    }

    // pass 1: xh.wh
#pragma unroll
    for (int s = 0; s < 4; ++s)
#pragma unroll
        for (int i = 0; i < 4; ++i)
#pragma unroll
            for (int t = 0; t < 2; ++t)
                cur[i * 2 + t] = __builtin_amdgcn_mfma_f32_16x16x32_f16(
                    Ah[i * 4 + s], bh[s * 2 + t], cur[i * 2 + t], 0, 0, 0);
    // pass 2: xl.wh (Al from wave-private LDS)
#pragma unroll
    for (int s = 0; s < 4; ++s) {
        f16x8 al[4];
#pragma unroll
        for (int i = 0; i < 4; ++i) al[i] = myAl[(i * 4 + s) * 64 + lane];
#pragma unroll
        for (int i = 0; i < 4; ++i)
#pragma unroll
            for (int t = 0; t < 2; ++t)
                cur[i * 2 + t] = __builtin_amdgcn_mfma_f32_16x16x32_f16(
                    al[i], bh[s * 2 + t], cur[i * 2 + t], 0, 0, 0);
    }

    // previous tile's score: independent of cur's MFMA chains -> the
    // scheduler slots these VALU ops between MFMA issues (pipe stays fed).
    if (SCORE_PREV) score_block(prev, prevTile, c, bestD, bestI);

    // pass 3: xh.wl
#pragma unroll
    for (int s = 0; s < 4; ++s)
#pragma unroll
        for (int i = 0; i < 4; ++i)
#pragma unroll
            for (int t = 0; t < 2; ++t)
                cur[i * 2 + t] = __builtin_amdgcn_mfma_f32_16x16x32_f16(
                    Ah[i * 4 + s], bl[s * 2 + t], cur[i * 2 + t], 0, 0, 0);
}

template <bool PARTIAL>
__global__ __launch_bounds__(256, 2) void som_main(
        const float* __restrict__ x, const f16x8* __restrict__ hG,
        const f16x8* __restrict__ lG, const float* __restrict__ wsq,
        const int* __restrict__ grid, int* __restrict__ out,
        unsigned long long* __restrict__ keys, unsigned* __restrict__ cnt,
        int unitGroups, int tilesQ, int tilesR, int N) {
    // Al (x-lo A-frags), wave-private: wave wv owns albuf[wv*1024 .. +1024)
    __shared__ f16x8 albuf[4 * 1024];   // 64 KB
    __shared__ int lastFlag;

    const int tid  = threadIdx.x;
    const int lane = tid & 63;
    const int wv   = tid >> 6;
    const int c    = lane & 15;   // frag col-class
    const int q    = lane >> 4;   // frag quad

    const int ug    = blockIdx.x % unitGroups;
    const int sg    = blockIdx.x / unitGroups;
    const int sWave = sg * 256 + wv * 64;   // this wave's 64 samples

    f16x8* myAl = &albuf[wv * 1024];

    // ---- A-frags: 64 samples x K=128. Ah resident (64 VGPRs); Al -> LDS.
    // A[m = lane&15][k = q*8 + j], m-tile i in 0..3, k-step s in 0..3.
    f16x8 Ah[16];
#pragma unroll
    for (int i = 0; i < 4; ++i) {
        const float* xr = x + (size_t)(sWave + 16 * i + c) * D + q * 8;
#pragma unroll
        for (int s = 0; s < 4; ++s) {
            float4 a0 = *reinterpret_cast<const float4*>(xr + 32 * s);
            float4 a1 = *reinterpret_cast<const float4*>(xr + 32 * s + 4);
            f16x8 h, l;
            cvt_split(a0, a1, h, l);
            Ah[i * 4 + s] = h;
            myAl[(i * 4 + s) * 64 + lane] = l;   // own slice only: no barrier
        }
    }

    float bestD[16];
    int   bestI[16];
#pragma unroll
    for (int sl = 0; sl < 16; ++sl) { bestD[sl] = -FLT_MAX; bestI[sl] = 0; }

    const int tile0  = ug * tilesQ + (ug < tilesR ? ug : tilesR);
    const int tcount = tilesQ + (ug < tilesR ? 1 : 0);

    f32x4 accA[8], accB[8];

    // tile 0: fill accA, nothing to score yet.
    tile_step<false>(Ah, myAl, lane, c, hG, lG, wsq, tile0,
                     accA, accB, 0, bestD, bestI);
    int tt = 1;
    for (; tt + 1 < tcount; tt += 2) {
        tile_step<true>(Ah, myAl, lane, c, hG, lG, wsq, tile0 + tt,
                        accB, accA, tile0 + tt - 1, bestD, bestI);
        tile_step<true>(Ah, myAl, lane, c, hG, lG, wsq, tile0 + tt + 1,
                        accA, accB, tile0 + tt, bestD, bestI);
    }
    if (tt < tcount) {   // even tcount: one trailing tile into accB
        tile_step<true>(Ah, myAl, lane, c, hG, lG, wsq, tile0 + tt,
                        accB, accA, tile0 + tt - 1, bestD, bestI);
        score_block(accB, tile0 + tt, c, bestD, bestI);
    } else {             // odd tcount: last tile already in accA
        score_block(accA, tile0 + tcount - 1, c, bestD, bestI);
    }

    // ---- reduce over the 16 col-classes (xor within each 16-lane q-group) ----
#pragma unroll
    for (int sl = 0; sl < 16; ++sl) {
        float d   = -2.0f * bestD[sl];   // exact: score = -2 * acc'
        int   idx = bestI[sl];
#pragma unroll
        for (int m = 1; m < 16; m <<= 1) {
            float od = __shfl_xor(d, m, 64);
            int   oi = __shfl_xor(idx, m, 64);
            if (od < d || (od == d && oi < idx)) { d = od; idx = oi; }
        }
        if (c == 0) {
            const int sOut = sWave + 16 * (sl >> 2) + 4 * q + (sl & 3);
            if (PARTIAL) {
                unsigned ub = __float_as_uint(d);
                ub = (ub & 0x80000000u) ? ~ub : (ub | 0x80000000u);  // monotone map
                unsigned long long key = ((unsigned long long)ub << 32) | (unsigned)idx;
                atomicMin(&keys[sOut], key);
            } else {
                out[2 * sOut]     = grid[2 * idx];
                out[2 * sOut + 1] = grid[2 * idx + 1];
            }
        }
    }

    if (PARTIAL) {
        // Last-arriving unit-group block for this sample group writes out.
        __threadfence();
        __syncthreads();
        if (tid == 0)
            lastFlag = (atomicAdd(&cnt[sg], 1u) == (unsigned)(unitGroups - 1));
        __syncthreads();
        if (lastFlag) {
            const int s0 = sg * 256 + tid;
            unsigned long long k = atomicMin(&keys[s0], ~0ull);  // atomic read
            int idx = (int)(unsigned)(k & 0xFFFFFFFFull);
            out[2 * s0]     = grid[2 * idx];
            out[2 * s0 + 1] = grid[2 * idx + 1];
        }
    }
}

extern "C" void kernel_launch(void* const* d_in, const int* in_sizes, int n_in,
                              void* d_out, int out_size, void* d_ws, size_t ws_size,
                              hipStream_t stream) {
    const float* x    = (const float*)d_in[0];
    const float* w    = (const float*)d_in[1];
    const int*   grid = (const int*)d_in[2];
    int* out = (int*)d_out;

    const int N = in_sizes[0] / D;   // 32768
    const int M = in_sizes[1] / D;   // 4096

    // ws layout: hG (1 MB) | lG (1 MB) | wsq (16 KB) | keys (N*8) | cnt
    const size_t hlBytes   = (size_t)M * D * 2;
    const size_t baseBytes = 2 * hlBytes + (size_t)M * 4;
    const int sampleGroups = N / 256;   // blocks of 4 waves x 64 samples
    const size_t needBytes = baseBytes + (size_t)N * 8 + (size_t)sampleGroups * 4;

    f16x8* hG  = (f16x8*)d_ws;
    f16x8* lG  = (f16x8*)((char*)d_ws + hlBytes);
    float* wsq = (float*)((char*)d_ws + 2 * hlBytes);
    unsigned long long* keys = (unsigned long long*)((char*)d_ws + baseBytes);
    unsigned* cnt = (unsigned*)((char*)d_ws + baseBytes + (size_t)N * 8);

    const int tiles = M / 32;           // 128
    const int UG = (ws_size >= needBytes) ? 4 : 1;   // 512 blocks = 2/CU

    prep_kernel<<<(M * 16 + 255) / 256, 256, 0, stream>>>(
        w, hG, lG, wsq, M,
        UG > 1 ? keys : nullptr, UG > 1 ? cnt : nullptr, N, sampleGroups);

    const int tq = tiles / UG, trm = tiles % UG;
    if (UG > 1) {
        som_main<true><<<sampleGroups * UG, 256, 0, stream>>>(
            x, hG, lG, wsq, grid, out, keys, cnt, UG, tq, trm, N);
    } else {
        som_main<false><<<sampleGroups, 256, 0, stream>>>(
            x, hG, lG, wsq, grid, out, nullptr, nullptr, 1, tiles, 0, N);
    }
}

// Round 4
// 184.916 us; speedup vs baseline: 1.4069x; 1.4069x over previous
//
#include <hip/hip_runtime.h>
#include <float.h>
#include <stdint.h>

// SOM2D argmin ||x-w||^2 via split-f16 MFMA. N=32768, M=4096, D=128.
//
// score = ||w||^2 - 2 x.w  (||x||^2 constant per sample: dropped)
// cross = xh*wh + xl*wh + xh*wl  (f16 hi/lo split, fp32 accum; |err|~2e-5)
//
// Round-10: B via LDS. Rounds 7/9 proved: hoisting B (or doubling acc) in
// registers spills (>256 live) and craters. Round-6's compiler schedule
// sinks B loads per-k-step -> ~8 exposed L2 waits/tile, both same-SIMD
// waves (same block, lockstep) stall together -> MfmaUtil 47.7%.
// Structural fix: stage the 16KB B tile into LDS ONCE PER BLOCK with
// global_load_lds (4x fewer L2 fetches), double-buffered, issued a full
// tile (~3k cyc) ahead. Register pressure DROPS (B granules stream from
// LDS). LDS: Al 3-of-4 k-steps (48KB, round-7's verified split; k-step 3
// in regs) + B dbuf 32KB = exactly 80KB -> 2 blocks/CU, and the 2 waves
// per SIMD are from DIFFERENT blocks (independent barriers) -> anti-phase:
// one block's score tail hides under the other's MFMA burst.
// No LDS flag (80KB is exact): last-wave writeout via per-wave atomicAdd
// on cnt[sg] with release/acquire threadfences.
// One __syncthreads per tile; its implicit vmcnt(0) drains the glds.
// ||w||^2 stays folded into acc init (round-9, correctness-verified).

constexpr int D = 128;

typedef _Float16 f16x8 __attribute__((ext_vector_type(8)));
typedef float    f32x4 __attribute__((ext_vector_type(4)));

__device__ __forceinline__ void glds16(const void* g, void* l) {
    __builtin_amdgcn_global_load_lds(
        (const __attribute__((address_space(1))) unsigned int*)g,
        (__attribute__((address_space(3))) unsigned int*)l, 16, 0, 0);
}

__device__ __forceinline__ void cvt_split(const float4& a0, const float4& a1,
                                          f16x8& h, f16x8& l) {
    float v[8] = {a0.x, a0.y, a0.z, a0.w, a1.x, a1.y, a1.z, a1.w};
#pragma unroll
    for (int j = 0; j < 8; ++j) {
        _Float16 hh = (_Float16)v[j];
        h[j] = hh;
        l[j] = (_Float16)(v[j] - (float)hh);
    }
}

// W (M x D fp32) -> frag-major hi/lo f16 + wsq. Thread = (unit u, k-octet o).
// Granule slot for (u, k=8o..8o+7), n-tile = 32 units:
//   T=u>>5, t=(u>>4)&1, c=u&15, s=o>>2, q=o&3
//   slot = T*512 + s*128 + t*64 + q*16 + c
// Main-loop read: tile_base(T*512) + s*128 + t*64 + lane. Sequential 1KB/instr.
// Also inits keys (u64 max) and per-sample-group completion counters.
__global__ __launch_bounds__(256) void prep_kernel(
        const float* __restrict__ w, f16x8* __restrict__ hG,
        f16x8* __restrict__ lG, float* __restrict__ wsq, int M,
        unsigned long long* __restrict__ keys, unsigned* __restrict__ cnt,
        int N, int nGroups) {
    int g = blockIdx.x * 256 + threadIdx.x;
    if (keys && g < N) keys[g] = ~0ull;
    if (cnt && g < nGroups) cnt[g] = 0u;
    if (g >= M * 16) return;
    int u = g >> 4, o = g & 15;
    const float4* wp = reinterpret_cast<const float4*>(w + (size_t)u * D + o * 8);
    float4 a0 = wp[0], a1 = wp[1];
    f16x8 h, l;
    cvt_split(a0, a1, h, l);
    float ss = 0.f;
    ss = fmaf(a0.x, a0.x, ss); ss = fmaf(a0.y, a0.y, ss);
    ss = fmaf(a0.z, a0.z, ss); ss = fmaf(a0.w, a0.w, ss);
    ss = fmaf(a1.x, a1.x, ss); ss = fmaf(a1.y, a1.y, ss);
    ss = fmaf(a1.z, a1.z, ss); ss = fmaf(a1.w, a1.w, ss);
#pragma unroll
    for (int m = 1; m < 16; m <<= 1) ss += __shfl_xor(ss, m, 64);
    if (o == 0) wsq[u] = ss;
    int slot = ((u >> 5) << 9) + ((o >> 2) << 7) + (((u >> 4) & 1) << 6)
             + ((o & 3) << 4) + (u & 15);
    hG[slot] = h;
    lG[slot] = l;
}

template <bool PARTIAL>
__global__ __launch_bounds__(256, 2) void som_main(
        const float* __restrict__ x, const f16x8* __restrict__ hG,
        const f16x8* __restrict__ lG, const float* __restrict__ wsq,
        const int* __restrict__ grid, int* __restrict__ out,
        unsigned long long* __restrict__ keys, unsigned* __restrict__ cnt,
        int unitGroups, int tilesQ, int tilesR, int N) {
    // Al (x-lo, k-steps 0..2), wave-private: wave wv owns albuf[wv*768..+768)
    __shared__ f16x8 albuf[4 * 768];    // 48 KB
    // B tile double buffer: buf b at Bbuf[b*1024]; granule g of the tile at
    // [b*1024 + g] for bh (g<512) and [b*1024 + 512 + g'] for bl.
    __shared__ f16x8 Bbuf[2 * 1024];    // 32 KB  (total 80 KB: 2 blocks/CU)

    const int tid  = threadIdx.x;
    const int lane = tid & 63;
    const int wv   = tid >> 6;
    const int c    = lane & 15;   // frag col-class
    const int q    = lane >> 4;   // frag quad

    const int ug    = blockIdx.x % unitGroups;
    const int sg    = blockIdx.x / unitGroups;
    const int sWave = sg * 256 + wv * 64;   // this wave's 64 samples

    f16x8* myAl = &albuf[wv * 768];

    // ---- A-frags: 64 samples x K=128. Ah resident (64 VGPRs);
    // Al k-steps 0..2 -> LDS (12 granules), k-step 3 -> regs (Al3).
    f16x8 Ah[16];
    f16x8 Al3[4];
#pragma unroll
    for (int i = 0; i < 4; ++i) {
        const float* xr = x + (size_t)(sWave + 16 * i + c) * D + q * 8;
#pragma unroll
        for (int s = 0; s < 4; ++s) {
            float4 a0 = *reinterpret_cast<const float4*>(xr + 32 * s);
            float4 a1 = *reinterpret_cast<const float4*>(xr + 32 * s + 4);
            f16x8 h, l;
            cvt_split(a0, a1, h, l);
            Ah[i * 4 + s] = h;
            if (s < 3) myAl[(i * 3 + s) * 64 + lane] = l;  // own slice: no barrier
            else       Al3[i] = l;
        }
    }

    float bestD[16];
    int   bestI[16];
#pragma unroll
    for (int sl = 0; sl < 16; ++sl) { bestD[sl] = -FLT_MAX; bestI[sl] = 0; }

    const int tile0  = ug * tilesQ + (ug < tilesR ? ug : tilesR);
    const int tcount = tilesQ + (ug < tilesR ? 1 : 0);

    // ---- stage: block cooperatively copies tile's 16KB (hG|lG) into Bbuf.
    // 16 chunks of 1KB; wave wv takes chunks wv*4..wv*4+3 (glds: LDS dest =
    // uniform base + lane*16; global src per-lane). Linear both sides.
    auto stage = [&](int tile, int buf) {
#pragma unroll
        for (int k2 = 0; k2 < 4; ++k2) {
            const int chunk = wv * 4 + k2;   // uniform per wave
            const f16x8* src = (chunk < 8)
                ? hG + ((size_t)tile << 9) + (size_t)chunk * 64 + lane
                : lG + ((size_t)tile << 9) + (size_t)(chunk - 8) * 64 + lane;
            glds16(src, &Bbuf[buf * 1024 + chunk * 64]);
        }
    };

    int cur = 0;
    stage(tile0, 0);
    __syncthreads();   // implicit vmcnt(0) drains the glds

    for (int tt = 0; tt < tcount; ++tt) {
        const int tile = tile0 + tt;
        if (tt + 1 < tcount) stage(tile + 1, cur ^ 1);   // ~3k cyc ahead

        const f16x8* bhB = &Bbuf[cur * 1024];
        const f16x8* blB = bhB + 512;

        const int uTile = tile * 32;
        const float m0 = -0.5f * wsq[uTile + c];
        const float m1 = -0.5f * wsq[uTile + 16 + c];

        f32x4 acc[8];   // [i*2 + t]
#pragma unroll
        for (int i = 0; i < 4; ++i) {
            acc[i * 2 + 0] = (f32x4){m0, m0, m0, m0};
            acc[i * 2 + 1] = (f32x4){m1, m1, m1, m1};
        }

        // pass 1: xh.wh  (bh streamed from LDS, 2 granules live)
#pragma unroll
        for (int s = 0; s < 4; ++s) {
            f16x8 b0 = bhB[s * 128 + lane];
            f16x8 b1 = bhB[s * 128 + 64 + lane];
#pragma unroll
            for (int i = 0; i < 4; ++i) {
                acc[i * 2 + 0] = __builtin_amdgcn_mfma_f32_16x16x32_f16(
                    Ah[i * 4 + s], b0, acc[i * 2 + 0], 0, 0, 0);
                acc[i * 2 + 1] = __builtin_amdgcn_mfma_f32_16x16x32_f16(
                    Ah[i * 4 + s], b1, acc[i * 2 + 1], 0, 0, 0);
            }
        }
        // pass 2: xl.wh  (al: s<3 from LDS, s==3 from regs; bh re-read)
#pragma unroll
        for (int s = 0; s < 4; ++s) {
            f16x8 b0 = bhB[s * 128 + lane];
            f16x8 b1 = bhB[s * 128 + 64 + lane];
            f16x8 al[4];
#pragma unroll
            for (int i = 0; i < 4; ++i)
                al[i] = (s < 3) ? myAl[(i * 3 + s) * 64 + lane] : Al3[i];
#pragma unroll
            for (int i = 0; i < 4; ++i) {
                acc[i * 2 + 0] = __builtin_amdgcn_mfma_f32_16x16x32_f16(
                    al[i], b0, acc[i * 2 + 0], 0, 0, 0);
                acc[i * 2 + 1] = __builtin_amdgcn_mfma_f32_16x16x32_f16(
                    al[i], b1, acc[i * 2 + 1], 0, 0, 0);
            }
        }
        // pass 3: xh.wl
#pragma unroll
        for (int s = 0; s < 4; ++s) {
            f16x8 b0 = blB[s * 128 + lane];
            f16x8 b1 = blB[s * 128 + 64 + lane];
#pragma unroll
            for (int i = 0; i < 4; ++i) {
                acc[i * 2 + 0] = __builtin_amdgcn_mfma_f32_16x16x32_f16(
                    Ah[i * 4 + s], b0, acc[i * 2 + 0], 0, 0, 0);
                acc[i * 2 + 1] = __builtin_amdgcn_mfma_f32_16x16x32_f16(
                    Ah[i * 4 + s], b1, acc[i * 2 + 1], 0, 0, 0);
            }
        }

        // all reads of Bbuf[cur] done; next tile's stage (into cur^1) was
        // issued at loop top. Barrier (implicit vmcnt(0)+lgkmcnt(0)) makes
        // the staged tile visible to all waves; then flip.
        __syncthreads();
        cur ^= 1;

        // score + per-lane argmax of acc' = -wq/2 + x.w  (score = -2*acc').
        // Post-barrier: overlaps the sibling block's MFMA burst.
        // C layout: row m = q*4+r (+16i), col = c (+16t). Strict > keeps
        // the first (lowest-index) unit on ties.
#pragma unroll
        for (int t = 0; t < 2; ++t) {
            const int n = uTile + 16 * t + c;
#pragma unroll
            for (int i = 0; i < 4; ++i) {
                f32x4 a = acc[i * 2 + t];
#pragma unroll
                for (int r = 0; r < 4; ++r) {
                    int sl = i * 4 + r;
                    if (a[r] > bestD[sl]) { bestD[sl] = a[r]; bestI[sl] = n; }
                }
            }
        }
    }

    // ---- reduce over the 16 col-classes (xor within each 16-lane q-group) ----
#pragma unroll
    for (int sl = 0; sl < 16; ++sl) {
        float d   = -2.0f * bestD[sl];   // exact: score = -2 * acc'
        int   idx = bestI[sl];
#pragma unroll
        for (int m = 1; m < 16; m <<= 1) {
            float od = __shfl_xor(d, m, 64);
            int   oi = __shfl_xor(idx, m, 64);
            if (od < d || (od == d && oi < idx)) { d = od; idx = oi; }
        }
        if (c == 0) {
            const int sOut = sWave + 16 * (sl >> 2) + 4 * q + (sl & 3);
            if (PARTIAL) {
                unsigned ub = __float_as_uint(d);
                ub = (ub & 0x80000000u) ? ~ub : (ub | 0x80000000u);  // monotone map
                unsigned long long key = ((unsigned long long)ub << 32) | (unsigned)idx;
                atomicMin(&keys[sOut], key);
            } else {
                out[2 * sOut]     = grid[2 * idx];
                out[2 * sOut + 1] = grid[2 * idx + 1];
            }
        }
    }

    if (PARTIAL) {
        // Per-wave completion protocol (no LDS flag: 80KB budget is exact).
        // release: my atomicMins precede my counter increment.
        __threadfence();
        int old = 0;
        if (lane == 0) old = (int)atomicAdd(&cnt[sg], 1u);
        old = __shfl(old, 0, 64);
        if (old == 4 * unitGroups - 1) {
            // acquire: all contributors' atomicMins visible before reads.
            __threadfence();
#pragma unroll
            for (int j = 0; j < 4; ++j) {
                const int s0 = sg * 256 + j * 64 + lane;
                unsigned long long k = atomicMin(&keys[s0], ~0ull);  // atomic read
                int idx = (int)(unsigned)(k & 0xFFFFFFFFull);
                out[2 * s0]     = grid[2 * idx];
                out[2 * s0 + 1] = grid[2 * idx + 1];
            }
        }
    }
}

extern "C" void kernel_launch(void* const* d_in, const int* in_sizes, int n_in,
                              void* d_out, int out_size, void* d_ws, size_t ws_size,
                              hipStream_t stream) {
    const float* x    = (const float*)d_in[0];
    const float* w    = (const float*)d_in[1];
    const int*   grid = (const int*)d_in[2];
    int* out = (int*)d_out;

    const int N = in_sizes[0] / D;   // 32768
    const int M = in_sizes[1] / D;   // 4096

    // ws layout: hG (1 MB) | lG (1 MB) | wsq (16 KB) | keys (N*8) | cnt
    const size_t hlBytes   = (size_t)M * D * 2;
    const size_t baseBytes = 2 * hlBytes + (size_t)M * 4;
    const int sampleGroups = N / 256;   // blocks of 4 waves x 64 samples
    const size_t needBytes = baseBytes + (size_t)N * 8 + (size_t)sampleGroups * 4;

    f16x8* hG  = (f16x8*)d_ws;
    f16x8* lG  = (f16x8*)((char*)d_ws + hlBytes);
    float* wsq = (float*)((char*)d_ws + 2 * hlBytes);
    unsigned long long* keys = (unsigned long long*)((char*)d_ws + baseBytes);
    unsigned* cnt = (unsigned*)((char*)d_ws + baseBytes + (size_t)N * 8);

    const int tiles = M / 32;           // 128
    const int UG = (ws_size >= needBytes) ? 4 : 1;   // 512 blocks = 2/CU

    prep_kernel<<<(M * 16 + 255) / 256, 256, 0, stream>>>(
        w, hG, lG, wsq, M,
        UG > 1 ? keys : nullptr, UG > 1 ? cnt : nullptr, N, sampleGroups);

    const int tq = tiles / UG, trm = tiles % UG;
    if (UG > 1) {
        som_main<true><<<sampleGroups * UG, 256, 0, stream>>>(
            x, hG, lG, wsq, grid, out, keys, cnt, UG, tq, trm, N);
    } else {
        som_main<false><<<sampleGroups, 256, 0, stream>>>(
            x, hG, lG, wsq, grid, out, nullptr, nullptr, 1, tiles, 0, N);
    }
}